// Round 2
// baseline (892.543 us; speedup 1.0000x reference)
//
#include <hip/hip_runtime.h>

#define NFEAT 128

// ---------------- LDS-privatized degree histogram (no global atomics) ----------------
// 32768 nodes/pass packed as 2 x u16 in u32 -> 64 KB LDS. Per-block partial counts
// written non-atomically; reduce kernel sums over blocks.
constexpr int HCHUNK = 32768;
constexpr int HBLOCKS = 64;

__global__ __launch_bounds__(256) void hist_k(const int* __restrict__ idx, int ne, int n,
                                              unsigned int* __restrict__ partials) {
    __shared__ unsigned int cnt[HCHUNK / 2];
    int b = blockIdx.x;
    int npass = (n + HCHUNK - 1) / HCHUNK;
    int per = (ne + HBLOCKS - 1) / HBLOCKS;
    int e0 = b * per, e1 = min(e0 + per, ne);
    for (int p = 0; p < npass; p++) {
        int base = p * HCHUNK;
        for (int i = threadIdx.x; i < HCHUNK / 2; i += 256) cnt[i] = 0;
        __syncthreads();
        for (int e = e0 + threadIdx.x; e < e1; e += 256) {
            int d = idx[e] - base;
            if ((unsigned)d < (unsigned)HCHUNK) {
                atomicAdd(&cnt[d >> 1], 1u << ((d & 1) * 16));
            }
        }
        __syncthreads();
        unsigned int* dstp = partials + ((size_t)p * HBLOCKS + b) * (HCHUNK / 2);
        for (int i = threadIdx.x; i < HCHUNK / 2; i += 256) dstp[i] = cnt[i];
        __syncthreads();
    }
}

__global__ void hist_reduce_k(const unsigned int* __restrict__ partials,
                              int* __restrict__ deg, int n) {
    int i = blockIdx.x * 256 + threadIdx.x;
    if (i >= n) return;
    int p = i / HCHUNK;
    int j = i - p * HCHUNK;
    const unsigned int* sp = partials + ((size_t)p * HBLOCKS) * (HCHUNK / 2) + (j >> 1);
    int sh = (j & 1) * 16;
    unsigned s = 0;
#pragma unroll 8
    for (int b = 0; b < HBLOCKS; b++) s += (sp[(size_t)b * (HCHUNK / 2)] >> sh) & 0xffffu;
    deg[i] = (int)s;
}

__global__ void norms_k(const int* __restrict__ dout, const int* __restrict__ din,
                        float* __restrict__ ns, float* __restrict__ nd, int n) {
    int i = blockIdx.x * 256 + threadIdx.x;
    if (i < n) {
        ns[i] = rsqrtf(fmaxf((float)dout[i], 1.f));
        nd[i] = rsqrtf(fmaxf((float)din[i], 1.f));
    }
}

// ---------------- exclusive scan of deg_in -> row_ptr (3 passes) ----------------
__global__ void scan1_k(const int* __restrict__ deg, int* __restrict__ rp,
                        int* __restrict__ partials, int n) {
    __shared__ int tmp[256];
    int t = threadIdx.x;
    int i = blockIdx.x * 256 + t;
    int v = (i < n) ? deg[i] : 0;
    tmp[t] = v;
    __syncthreads();
    int val = v;
    for (int off = 1; off < 256; off <<= 1) {
        int add = (t >= off) ? tmp[t - off] : 0;
        __syncthreads();
        val += add;
        tmp[t] = val;
        __syncthreads();
    }
    if (i < n) rp[i] = val - v;              // chunk-local exclusive
    if (t == 255) partials[blockIdx.x] = val; // chunk total
}

__global__ void scan2_k(int* __restrict__ partials, int nb) {
    __shared__ int tmp[512];
    int t = threadIdx.x;
    int v = (t < nb) ? partials[t] : 0;
    tmp[t] = v;
    __syncthreads();
    int val = v;
    for (int off = 1; off < 512; off <<= 1) {
        int add = (t >= off) ? tmp[t - off] : 0;
        __syncthreads();
        val += add;
        tmp[t] = val;
        __syncthreads();
    }
    if (t < nb) partials[t] = val - v;        // exclusive over chunks
}

__global__ void scan3_k(int* __restrict__ rp, const int* __restrict__ partials,
                        const int* __restrict__ deg, int n) {
    int i = blockIdx.x * 256 + threadIdx.x;
    if (i < n) {
        int r = rp[i] + partials[blockIdx.x];
        rp[i] = r;
        if (i == n - 1) rp[n] = r + deg[i];
    }
}

__global__ void copy_cur_k(const int* __restrict__ rp, int* __restrict__ cur, int n) {
    int i = blockIdx.x * 256 + threadIdx.x;
    if (i < n) cur[i] = rp[i];
}

__global__ void fill_k(const int* __restrict__ src, const int* __restrict__ dst,
                       int* __restrict__ cur, int* __restrict__ esrc, int ne) {
    int e = blockIdx.x * 256 + threadIdx.x;
    if (e < ne) {
        int p = atomicAdd(&cur[dst[e]], 1);   // cur pre-initialized to rp
        esrc[p] = src[e];
    }
}

// ---------------- GEMM: H[m][c] = sum_k (X[m][k]*rs[m]) * W[k][c]  (+ rs[m]*v[c]) ----
template <int NCOL, bool HAS_V>
__global__ __launch_bounds__(256) void gemm_k(
    const float* __restrict__ X, const float* __restrict__ W,
    const float* __restrict__ rs, const float* __restrict__ vvec,
    float* __restrict__ H, int n) {
    constexpr int BK = 32;
    constexpr int CG = NCOL / 4;   // threads along columns
    constexpr int RG = 256 / CG;   // threads along rows
    constexpr int BM = RG * 4;     // rows per block (128->32, 64->64)
    __shared__ float Xs[BK][BM + 4];   // transposed x tile, padded
    __shared__ float Ws[BK][NCOL];
    int tid = threadIdx.x;
    int tx = tid % CG;
    int ty = tid / CG;
    int row0 = blockIdx.x * BM;
    float acc[4][4] = {};
    for (int k0 = 0; k0 < NFEAT; k0 += BK) {
        for (int idx = tid; idx < BK * NCOL; idx += 256) {
            int k = idx / NCOL, c = idx % NCOL;
            Ws[k][c] = W[(k0 + k) * NCOL + c];
        }
        for (int idx = tid; idx < BM * BK; idx += 256) {
            int m = idx / BK, k = idx % BK;
            int gm = row0 + m;
            Xs[k][m] = (gm < n) ? X[(size_t)gm * NFEAT + k0 + k] * rs[gm] : 0.f;
        }
        __syncthreads();
#pragma unroll
        for (int k = 0; k < BK; k++) {
            float4 a = *(const float4*)&Xs[k][ty * 4];
            float4 b = *(const float4*)&Ws[k][tx * 4];
            float av[4] = {a.x, a.y, a.z, a.w};
            float bv[4] = {b.x, b.y, b.z, b.w};
#pragma unroll
            for (int i = 0; i < 4; i++)
#pragma unroll
                for (int j = 0; j < 4; j++) acc[i][j] += av[i] * bv[j];
        }
        __syncthreads();
    }
#pragma unroll
    for (int i = 0; i < 4; i++) {
        int gm = row0 + ty * 4 + i;
        if (gm < n) {
            float4 o;
            o.x = acc[i][0]; o.y = acc[i][1]; o.z = acc[i][2]; o.w = acc[i][3];
            if (HAS_V) {
                float sc = rs[gm];
                o.x += sc * vvec[tx * 4 + 0];
                o.y += sc * vvec[tx * 4 + 1];
                o.z += sc * vvec[tx * 4 + 2];
                o.w += sc * vvec[tx * 4 + 3];
            }
            *(float4*)&H[(size_t)gm * NCOL + tx * 4] = o;
        }
    }
}

// ---------------- CSR aggregation: out[n][c] = act(nd[n]*sum_e H[esrc][c] + b[c]) ----
template <int F, bool RELU>
__global__ void agg_k(const float* __restrict__ H, const int* __restrict__ rp,
                      const int* __restrict__ esrc, const float* __restrict__ nd,
                      const float* __restrict__ bias, float* __restrict__ out) {
    int node = blockIdx.x;
    int c = threadIdx.x;
    int e0 = rp[node], e1 = rp[node + 1];
    float acc = 0.f;
    int e = e0;
    for (; e + 4 <= e1; e += 4) {
        int s0 = esrc[e], s1 = esrc[e + 1], s2 = esrc[e + 2], s3 = esrc[e + 3];
        float v0 = H[(size_t)s0 * F + c];
        float v1 = H[(size_t)s1 * F + c];
        float v2 = H[(size_t)s2 * F + c];
        float v3 = H[(size_t)s3 * F + c];
        acc += (v0 + v1) + (v2 + v3);
    }
    for (; e < e1; e++) acc += H[(size_t)esrc[e] * F + c];
    float val = acc * nd[node] + bias[c];
    if (RELU) val = fmaxf(val, 0.f);
    out[(size_t)node * F + c] = val;
}

// ---------------- BN stats + fold into W2 ----------------
__global__ void colstats_k(const float* __restrict__ X, float* __restrict__ colsum,
                           float* __restrict__ colsq, int n) {
    int c = threadIdx.x;  // 128 threads
    int r0 = blockIdx.x * 512;
    int r1 = min(r0 + 512, n);
    float s = 0.f, sq = 0.f;
    for (int r = r0; r < r1; r++) {
        float v = X[(size_t)r * 128 + c];
        s += v;
        sq += v * v;
    }
    atomicAdd(&colsum[c], s);
    atomicAdd(&colsq[c], sq);
}

__global__ void bn_prep_k(const float* __restrict__ colsum, const float* __restrict__ colsq,
                          const float* __restrict__ gamma, const float* __restrict__ beta,
                          const float* __restrict__ W2, float* __restrict__ W2p,
                          float* __restrict__ v2, float n) {
    __shared__ float s_s[128], s_t[128];
    int c = threadIdx.x;  // 128 threads
    float mu = colsum[c] / n;
    float var = colsq[c] / n - mu * mu;
    float s = gamma[c] * rsqrtf(var + 1e-5f);
    float t = beta[c] - mu * s;
    s_s[c] = s;
    s_t[c] = t;
    __syncthreads();
    float acc = 0.f;
    for (int k = 0; k < 128; k++) {
        float w = W2[k * 128 + c];
        W2p[k * 128 + c] = s_s[k] * w;
        acc += s_t[k] * w;
    }
    v2[c] = acc;
}

extern "C" void kernel_launch(void* const* d_in, const int* in_sizes, int n_in,
                              void* d_out, int out_size, void* d_ws, size_t ws_size,
                              hipStream_t stream) {
    const float* feat = (const float*)d_in[0];
    const int* src = (const int*)d_in[1];
    const int* dst = (const int*)d_in[2];
    const float* W1 = (const float*)d_in[3];
    const float* b1 = (const float*)d_in[4];
    const float* gamma1 = (const float*)d_in[5];
    const float* beta1 = (const float*)d_in[6];
    const float* W2 = (const float*)d_in[7];
    const float* b2 = (const float*)d_in[8];
    const float* W3 = (const float*)d_in[9];
    const float* b3 = (const float*)d_in[10];
    float* out = (float*)d_out;

    int n = in_sizes[0] / NFEAT;
    int ne = in_sizes[1];

    char* ws = (char*)d_ws;
    size_t off = 0;
    auto carve = [&](size_t bytes) -> void* {
        void* p = ws + off;
        off += (bytes + 255) & ~(size_t)255;
        return p;
    };
    float* h    = (float*)carve((size_t)n * NFEAT * 4);
    float* x    = (float*)carve((size_t)n * NFEAT * 4);
    int* esrc   = (int*)carve((size_t)ne * 4);
    int* dout_  = (int*)carve((size_t)n * 4);
    int* din_   = (int*)carve((size_t)n * 4);
    float* ns   = (float*)carve((size_t)n * 4);
    float* ndv  = (float*)carve((size_t)n * 4);
    int* rp     = (int*)carve((size_t)(n + 1) * 4);
    int* cur    = (int*)carve((size_t)n * 4);
    int* parts  = (int*)carve(512 * 4);
    float* colsum = (float*)carve(128 * 4);
    float* colsq  = (float*)carve(128 * 4);
    float* W2p  = (float*)carve(128 * 128 * 4);
    float* v2   = (float*)carve(128 * 4);

    // histogram partials alias h (h is first written by gemm1, after CSR build)
    unsigned int* hpart = (unsigned int*)h;

    hipMemsetAsync(colsum, 0, 128 * 4, stream);
    hipMemsetAsync(colsq, 0, 128 * 4, stream);

    int ebl = (ne + 255) / 256;
    int nbl = (n + 255) / 256;

    // degrees via LDS histograms (no global atomics)
    hist_k<<<HBLOCKS, 256, 0, stream>>>(src, ne, n, hpart);
    hist_reduce_k<<<nbl, 256, 0, stream>>>(hpart, dout_, n);
    hist_k<<<HBLOCKS, 256, 0, stream>>>(dst, ne, n, hpart);
    hist_reduce_k<<<nbl, 256, 0, stream>>>(hpart, din_, n);

    norms_k<<<nbl, 256, 0, stream>>>(dout_, din_, ns, ndv, n);
    scan1_k<<<nbl, 256, 0, stream>>>(din_, rp, parts, n);
    scan2_k<<<1, 512, 0, stream>>>(parts, nbl);
    scan3_k<<<nbl, 256, 0, stream>>>(rp, parts, din_, n);
    copy_cur_k<<<nbl, 256, 0, stream>>>(rp, cur, n);
    fill_k<<<ebl, 256, 0, stream>>>(src, dst, cur, esrc, ne);

    // layer 1: relu(conv(features, W1, b1))
    gemm_k<128, false><<<(n + 31) / 32, 256, 0, stream>>>(feat, W1, ns, nullptr, h, n);
    agg_k<128, true><<<n, 128, 0, stream>>>(h, rp, esrc, ndv, b1, x);

    // batchnorm folded into W2
    colstats_k<<<(n + 511) / 512, 128, 0, stream>>>(x, colsum, colsq, n);
    bn_prep_k<<<1, 128, 0, stream>>>(colsum, colsq, gamma1, beta1, W2, W2p, v2, (float)n);

    // layer 2: relu(conv(BN(x), W2, b2))
    gemm_k<128, true><<<(n + 31) / 32, 256, 0, stream>>>(x, W2p, ns, v2, h, n);
    agg_k<128, true><<<n, 128, 0, stream>>>(h, rp, esrc, ndv, b2, x);

    // layer 3: conv(x, W3, b3) -> out
    gemm_k<64, false><<<(n + 63) / 64, 256, 0, stream>>>(x, W3, ns, nullptr, h, n);
    agg_k<64, false><<<n, 64, 0, stream>>>(h, rp, esrc, ndv, b3, out);
}

// Round 3
// 836.168 us; speedup vs baseline: 1.0674x; 1.0674x over previous
//
#include <hip/hip_runtime.h>

#define NFEAT 128

// ---------------- LDS-privatized degree histogram (no global atomics) ----------------
// 32768 nodes/pass packed as 2 x u16 in u32 -> 64 KB LDS per block.
constexpr int HCHUNK = 32768;
constexpr int HBLOCKS = 128;

__global__ __launch_bounds__(256) void hist_k(const int* __restrict__ idx, int ne, int n,
                                              unsigned int* __restrict__ partials) {
    __shared__ unsigned int cnt[HCHUNK / 2];
    int b = blockIdx.x;
    int npass = (n + HCHUNK - 1) / HCHUNK;
    int per = (ne + HBLOCKS - 1) / HBLOCKS;
    int e0 = b * per, e1 = min(e0 + per, ne);
    for (int p = 0; p < npass; p++) {
        int base = p * HCHUNK;
        for (int i = threadIdx.x; i < HCHUNK / 2; i += 256) cnt[i] = 0;
        __syncthreads();
        for (int e = e0 + threadIdx.x; e < e1; e += 256) {
            int d = idx[e] - base;
            if ((unsigned)d < (unsigned)HCHUNK) {
                atomicAdd(&cnt[d >> 1], 1u << ((d & 1) * 16));
            }
        }
        __syncthreads();
        unsigned int* dstp = partials + ((size_t)p * HBLOCKS + b) * (HCHUNK / 2);
        for (int i = threadIdx.x; i < HCHUNK / 2; i += 256) dstp[i] = cnt[i];
        __syncthreads();
    }
}

// Sum partials over blocks -> deg[node]; optionally rewrite partials in place with the
// EXCLUSIVE per-block prefix (stable counting-sort offsets). One thread per u32 slot
// (2 packed nodes) so the in-place write has no races.
template <bool PFX>
__global__ void sum_prefix_k(unsigned int* __restrict__ partials, int* __restrict__ deg,
                             int n, int npass) {
    int slot = blockIdx.x * 256 + threadIdx.x;
    int total = npass * (HCHUNK / 2);
    if (slot >= total) return;
    int p = slot / (HCHUNK / 2);
    int j2 = slot - p * (HCHUNK / 2);
    unsigned int* base = partials + (size_t)p * HBLOCKS * (HCHUNK / 2) + j2;
    unsigned lo = 0, hi = 0;
    for (int b = 0; b < HBLOCKS; b++) {
        unsigned v = base[(size_t)b * (HCHUNK / 2)];
        if (PFX) base[(size_t)b * (HCHUNK / 2)] = lo | (hi << 16);
        lo += v & 0xffffu;
        hi += v >> 16;
    }
    int node = p * HCHUNK + 2 * j2;
    if (node < n) deg[node] = (int)lo;
    if (node + 1 < n) deg[node + 1] = (int)hi;
}

__global__ void norms_k(const int* __restrict__ dout, const int* __restrict__ din,
                        float* __restrict__ ns, float* __restrict__ nd, int n) {
    int i = blockIdx.x * 256 + threadIdx.x;
    if (i < n) {
        ns[i] = rsqrtf(fmaxf((float)dout[i], 1.f));
        nd[i] = rsqrtf(fmaxf((float)din[i], 1.f));
    }
}

// ---------------- exclusive scan of deg_in -> row_ptr (3 passes) ----------------
__global__ void scan1_k(const int* __restrict__ deg, int* __restrict__ rp,
                        int* __restrict__ partials, int n) {
    __shared__ int tmp[256];
    int t = threadIdx.x;
    int i = blockIdx.x * 256 + t;
    int v = (i < n) ? deg[i] : 0;
    tmp[t] = v;
    __syncthreads();
    int val = v;
    for (int off = 1; off < 256; off <<= 1) {
        int add = (t >= off) ? tmp[t - off] : 0;
        __syncthreads();
        val += add;
        tmp[t] = val;
        __syncthreads();
    }
    if (i < n) rp[i] = val - v;
    if (t == 255) partials[blockIdx.x] = val;
}

__global__ void scan2_k(int* __restrict__ partials, int nb) {
    __shared__ int tmp[512];
    int t = threadIdx.x;
    int v = (t < nb) ? partials[t] : 0;
    tmp[t] = v;
    __syncthreads();
    int val = v;
    for (int off = 1; off < 512; off <<= 1) {
        int add = (t >= off) ? tmp[t - off] : 0;
        __syncthreads();
        val += add;
        tmp[t] = val;
        __syncthreads();
    }
    if (t < nb) partials[t] = val - v;
}

__global__ void scan3_k(int* __restrict__ rp, const int* __restrict__ partials,
                        const int* __restrict__ deg, int n) {
    int i = blockIdx.x * 256 + threadIdx.x;
    if (i < n) {
        int r = rp[i] + partials[blockIdx.x];
        rp[i] = r;
        if (i == n - 1) rp[n] = r + deg[i];
    }
}

// ---------------- atomic-free CSR fill (counting-sort scatter) ----------------
__global__ __launch_bounds__(256) void fill2_k(const int* __restrict__ src,
                                               const int* __restrict__ dst,
                                               const int* __restrict__ rp,
                                               const unsigned int* __restrict__ prefix,
                                               int* __restrict__ esrc, int ne, int n) {
    __shared__ unsigned int cnt[HCHUNK / 2];
    int b = blockIdx.x;
    int npass = (n + HCHUNK - 1) / HCHUNK;
    int per = (ne + HBLOCKS - 1) / HBLOCKS;
    int e0 = b * per, e1 = min(e0 + per, ne);
    for (int p = 0; p < npass; p++) {
        int base = p * HCHUNK;
        for (int i = threadIdx.x; i < HCHUNK / 2; i += 256) cnt[i] = 0;
        __syncthreads();
        const unsigned int* pf = prefix + ((size_t)p * HBLOCKS + b) * (HCHUNK / 2);
        for (int e = e0 + threadIdx.x; e < e1; e += 256) {
            int d = dst[e] - base;
            if ((unsigned)d < (unsigned)HCHUNK) {
                int sh = (d & 1) * 16;
                unsigned old = atomicAdd(&cnt[d >> 1], 1u << sh);  // LDS atomic only
                int rank = (int)((old >> sh) & 0xffffu);
                int pos = rp[base + d] + (int)((pf[d >> 1] >> sh) & 0xffffu) + rank;
                esrc[pos] = src[e];
            }
        }
        __syncthreads();
    }
}

// ---------------- GEMM: H[m][c] = sum_k (X[m][k]*rs[m]) * W[k][c]  (+ rs[m]*v[c]) ----
template <int NCOL, bool HAS_V>
__global__ __launch_bounds__(256) void gemm_k(
    const float* __restrict__ X, const float* __restrict__ W,
    const float* __restrict__ rs, const float* __restrict__ vvec,
    float* __restrict__ H, int n) {
    constexpr int BK = 32;
    constexpr int CG = NCOL / 4;
    constexpr int RG = 256 / CG;
    constexpr int BM = RG * 4;
    __shared__ float Xs[BK][BM + 4];
    __shared__ float Ws[BK][NCOL];
    int tid = threadIdx.x;
    int tx = tid % CG;
    int ty = tid / CG;
    int row0 = blockIdx.x * BM;
    float acc[4][4] = {};
    for (int k0 = 0; k0 < NFEAT; k0 += BK) {
        for (int idx = tid; idx < BK * NCOL; idx += 256) {
            int k = idx / NCOL, c = idx % NCOL;
            Ws[k][c] = W[(k0 + k) * NCOL + c];
        }
        for (int idx = tid; idx < BM * BK; idx += 256) {
            int m = idx / BK, k = idx % BK;
            int gm = row0 + m;
            Xs[k][m] = (gm < n) ? X[(size_t)gm * NFEAT + k0 + k] * rs[gm] : 0.f;
        }
        __syncthreads();
#pragma unroll
        for (int k = 0; k < BK; k++) {
            float4 a = *(const float4*)&Xs[k][ty * 4];
            float4 b = *(const float4*)&Ws[k][tx * 4];
            float av[4] = {a.x, a.y, a.z, a.w};
            float bv[4] = {b.x, b.y, b.z, b.w};
#pragma unroll
            for (int i = 0; i < 4; i++)
#pragma unroll
                for (int j = 0; j < 4; j++) acc[i][j] += av[i] * bv[j];
        }
        __syncthreads();
    }
#pragma unroll
    for (int i = 0; i < 4; i++) {
        int gm = row0 + ty * 4 + i;
        if (gm < n) {
            float4 o;
            o.x = acc[i][0]; o.y = acc[i][1]; o.z = acc[i][2]; o.w = acc[i][3];
            if (HAS_V) {
                float sc = rs[gm];
                o.x += sc * vvec[tx * 4 + 0];
                o.y += sc * vvec[tx * 4 + 1];
                o.z += sc * vvec[tx * 4 + 2];
                o.w += sc * vvec[tx * 4 + 3];
            }
            *(float4*)&H[(size_t)gm * NCOL + tx * 4] = o;
        }
    }
}

// ---------------- CSR aggregation: out[n][c] = act(nd[n]*sum_e H[esrc][c] + b[c]) ----
template <int F, bool RELU>
__global__ void agg_k(const float* __restrict__ H, const int* __restrict__ rp,
                      const int* __restrict__ esrc, const float* __restrict__ nd,
                      const float* __restrict__ bias, float* __restrict__ out) {
    int node = blockIdx.x;
    int c = threadIdx.x;
    int e0 = rp[node], e1 = rp[node + 1];
    float acc = 0.f;
    int e = e0;
    for (; e + 4 <= e1; e += 4) {
        int s0 = esrc[e], s1 = esrc[e + 1], s2 = esrc[e + 2], s3 = esrc[e + 3];
        float v0 = H[(size_t)s0 * F + c];
        float v1 = H[(size_t)s1 * F + c];
        float v2 = H[(size_t)s2 * F + c];
        float v3 = H[(size_t)s3 * F + c];
        acc += (v0 + v1) + (v2 + v3);
    }
    for (; e < e1; e++) acc += H[(size_t)esrc[e] * F + c];
    float val = acc * nd[node] + bias[c];
    if (RELU) val = fmaxf(val, 0.f);
    out[(size_t)node * F + c] = val;
}

// ---------------- BN stats + fold into W2 ----------------
__global__ void colstats_k(const float* __restrict__ X, float* __restrict__ colsum,
                           float* __restrict__ colsq, int n) {
    int c = threadIdx.x;
    int r0 = blockIdx.x * 512;
    int r1 = min(r0 + 512, n);
    float s = 0.f, sq = 0.f;
    for (int r = r0; r < r1; r++) {
        float v = X[(size_t)r * 128 + c];
        s += v;
        sq += v * v;
    }
    atomicAdd(&colsum[c], s);
    atomicAdd(&colsq[c], sq);
}

__global__ void bn_prep_k(const float* __restrict__ colsum, const float* __restrict__ colsq,
                          const float* __restrict__ gamma, const float* __restrict__ beta,
                          const float* __restrict__ W2, float* __restrict__ W2p,
                          float* __restrict__ v2, float n) {
    __shared__ float s_s[128], s_t[128];
    int c = threadIdx.x;
    float mu = colsum[c] / n;
    float var = colsq[c] / n - mu * mu;
    float s = gamma[c] * rsqrtf(var + 1e-5f);
    float t = beta[c] - mu * s;
    s_s[c] = s;
    s_t[c] = t;
    __syncthreads();
    float acc = 0.f;
    for (int k = 0; k < 128; k++) {
        float w = W2[k * 128 + c];
        W2p[k * 128 + c] = s_s[k] * w;
        acc += s_t[k] * w;
    }
    v2[c] = acc;
}

extern "C" void kernel_launch(void* const* d_in, const int* in_sizes, int n_in,
                              void* d_out, int out_size, void* d_ws, size_t ws_size,
                              hipStream_t stream) {
    const float* feat = (const float*)d_in[0];
    const int* src = (const int*)d_in[1];
    const int* dst = (const int*)d_in[2];
    const float* W1 = (const float*)d_in[3];
    const float* b1 = (const float*)d_in[4];
    const float* gamma1 = (const float*)d_in[5];
    const float* beta1 = (const float*)d_in[6];
    const float* W2 = (const float*)d_in[7];
    const float* b2 = (const float*)d_in[8];
    const float* W3 = (const float*)d_in[9];
    const float* b3 = (const float*)d_in[10];
    float* out = (float*)d_out;

    int n = in_sizes[0] / NFEAT;
    int ne = in_sizes[1];
    int npass = (n + HCHUNK - 1) / HCHUNK;

    char* ws = (char*)d_ws;
    size_t off = 0;
    auto carve = [&](size_t bytes) -> void* {
        void* p = ws + off;
        off += (bytes + 255) & ~(size_t)255;
        return p;
    };
    float* h    = (float*)carve((size_t)n * NFEAT * 4);
    float* x    = (float*)carve((size_t)n * NFEAT * 4);
    int* esrc   = (int*)carve((size_t)ne * 4);
    int* dout_  = (int*)carve((size_t)n * 4);
    int* din_   = (int*)carve((size_t)n * 4);
    float* ns   = (float*)carve((size_t)n * 4);
    float* ndv  = (float*)carve((size_t)n * 4);
    int* rp     = (int*)carve((size_t)(n + 1) * 4);
    int* parts  = (int*)carve(512 * 4);
    float* colsum = (float*)carve(128 * 4);
    float* colsq  = (float*)carve(128 * 4);
    float* W2p  = (float*)carve(128 * 128 * 4);
    float* v2   = (float*)carve(128 * 4);

    // histogram partials alias h (h first written by gemm1, after CSR build)
    unsigned int* hpart = (unsigned int*)h;

    hipMemsetAsync(colsum, 0, 128 * 4, stream);
    hipMemsetAsync(colsq, 0, 128 * 4, stream);

    int ebl = (ne + 255) / 256;
    int nbl = (n + 255) / 256;
    int sbl = (npass * (HCHUNK / 2) + 255) / 256;

    // deg_out (src histogram, sum only)
    hist_k<<<HBLOCKS, 256, 0, stream>>>(src, ne, n, hpart);
    sum_prefix_k<false><<<sbl, 256, 0, stream>>>(hpart, dout_, n, npass);
    // deg_in (dst histogram) + in-place per-block exclusive prefix
    hist_k<<<HBLOCKS, 256, 0, stream>>>(dst, ne, n, hpart);
    sum_prefix_k<true><<<sbl, 256, 0, stream>>>(hpart, din_, n, npass);

    norms_k<<<nbl, 256, 0, stream>>>(dout_, din_, ns, ndv, n);
    scan1_k<<<nbl, 256, 0, stream>>>(din_, rp, parts, n);
    scan2_k<<<1, 512, 0, stream>>>(parts, nbl);
    scan3_k<<<nbl, 256, 0, stream>>>(rp, parts, din_, n);
    fill2_k<<<HBLOCKS, 256, 0, stream>>>(src, dst, rp, hpart, esrc, ne, n);

    // layer 1: relu(conv(features, W1, b1))
    gemm_k<128, false><<<(n + 31) / 32, 256, 0, stream>>>(feat, W1, ns, nullptr, h, n);
    agg_k<128, true><<<n, 128, 0, stream>>>(h, rp, esrc, ndv, b1, x);

    // batchnorm folded into W2
    colstats_k<<<(n + 511) / 512, 128, 0, stream>>>(x, colsum, colsq, n);
    bn_prep_k<<<1, 128, 0, stream>>>(colsum, colsq, gamma1, beta1, W2, W2p, v2, (float)n);

    // layer 2: relu(conv(BN(x), W2, b2))
    gemm_k<128, true><<<(n + 31) / 32, 256, 0, stream>>>(x, W2p, ns, v2, h, n);
    agg_k<128, true><<<n, 128, 0, stream>>>(h, rp, esrc, ndv, b2, x);

    // layer 3: conv(x, W3, b3) -> out
    gemm_k<64, false><<<(n + 63) / 64, 256, 0, stream>>>(x, W3, ns, nullptr, h, n);
    agg_k<64, false><<<n, 64, 0, stream>>>(h, rp, esrc, ndv, b3, out);
}

// Round 4
// 729.526 us; speedup vs baseline: 1.2235x; 1.1462x over previous
//
#include <hip/hip_runtime.h>

#define NFEAT 128

// ---------------- LDS-privatized degree histogram (no global atomics) ----------------
constexpr int HCHUNK = 32768;
constexpr int HBLOCKS = 128;

__global__ __launch_bounds__(256) void hist_k(const int* __restrict__ idx, int ne, int n,
                                              unsigned int* __restrict__ partials) {
    __shared__ unsigned int cnt[HCHUNK / 2];
    int b = blockIdx.x;
    int npass = (n + HCHUNK - 1) / HCHUNK;
    int per = (ne + HBLOCKS - 1) / HBLOCKS;
    int e0 = b * per, e1 = min(e0 + per, ne);
    for (int p = 0; p < npass; p++) {
        int base = p * HCHUNK;
        for (int i = threadIdx.x; i < HCHUNK / 2; i += 256) cnt[i] = 0;
        __syncthreads();
        for (int e = e0 + threadIdx.x; e < e1; e += 256) {
            int d = idx[e] - base;
            if ((unsigned)d < (unsigned)HCHUNK) {
                atomicAdd(&cnt[d >> 1], 1u << ((d & 1) * 16));
            }
        }
        __syncthreads();
        unsigned int* dstp = partials + ((size_t)p * HBLOCKS + b) * (HCHUNK / 2);
        for (int i = threadIdx.x; i < HCHUNK / 2; i += 256) dstp[i] = cnt[i];
        __syncthreads();
    }
}

template <bool PFX>
__global__ void sum_prefix_k(unsigned int* __restrict__ partials, int* __restrict__ deg,
                             int n, int npass) {
    int slot = blockIdx.x * 256 + threadIdx.x;
    int total = npass * (HCHUNK / 2);
    if (slot >= total) return;
    int p = slot / (HCHUNK / 2);
    int j2 = slot - p * (HCHUNK / 2);
    unsigned int* base = partials + (size_t)p * HBLOCKS * (HCHUNK / 2) + j2;
    unsigned lo = 0, hi = 0;
    for (int b = 0; b < HBLOCKS; b++) {
        unsigned v = base[(size_t)b * (HCHUNK / 2)];
        if (PFX) base[(size_t)b * (HCHUNK / 2)] = lo | (hi << 16);
        lo += v & 0xffffu;
        hi += v >> 16;
    }
    int node = p * HCHUNK + 2 * j2;
    if (node < n) deg[node] = (int)lo;
    if (node + 1 < n) deg[node + 1] = (int)hi;
}

__global__ void norms_k(const int* __restrict__ dout, const int* __restrict__ din,
                        float* __restrict__ ns, float* __restrict__ nd, int n) {
    int i = blockIdx.x * 256 + threadIdx.x;
    if (i < n) {
        ns[i] = rsqrtf(fmaxf((float)dout[i], 1.f));
        nd[i] = rsqrtf(fmaxf((float)din[i], 1.f));
    }
}

// ---------------- exclusive scan of deg_in -> row_ptr ----------------
__global__ void scan1_k(const int* __restrict__ deg, int* __restrict__ rp,
                        int* __restrict__ partials, int n) {
    __shared__ int tmp[256];
    int t = threadIdx.x;
    int i = blockIdx.x * 256 + t;
    int v = (i < n) ? deg[i] : 0;
    tmp[t] = v;
    __syncthreads();
    int val = v;
    for (int off = 1; off < 256; off <<= 1) {
        int add = (t >= off) ? tmp[t - off] : 0;
        __syncthreads();
        val += add;
        tmp[t] = val;
        __syncthreads();
    }
    if (i < n) rp[i] = val - v;
    if (t == 255) partials[blockIdx.x] = val;
}

__global__ void scan2_k(int* __restrict__ partials, int nb) {
    __shared__ int tmp[512];
    int t = threadIdx.x;
    int v = (t < nb) ? partials[t] : 0;
    tmp[t] = v;
    __syncthreads();
    int val = v;
    for (int off = 1; off < 512; off <<= 1) {
        int add = (t >= off) ? tmp[t - off] : 0;
        __syncthreads();
        val += add;
        tmp[t] = val;
        __syncthreads();
    }
    if (t < nb) partials[t] = val - v;
}

__global__ void scan3_k(int* __restrict__ rp, const int* __restrict__ partials,
                        const int* __restrict__ deg, int n) {
    int i = blockIdx.x * 256 + threadIdx.x;
    if (i < n) {
        int r = rp[i] + partials[blockIdx.x];
        rp[i] = r;
        if (i == n - 1) rp[n] = r + deg[i];
    }
}

// ---------------- atomic-free CSR fill (counting-sort scatter) ----------------
__global__ __launch_bounds__(256) void fill2_k(const int* __restrict__ src,
                                               const int* __restrict__ dst,
                                               const int* __restrict__ rp,
                                               const unsigned int* __restrict__ prefix,
                                               int* __restrict__ esrc, int ne, int n) {
    __shared__ unsigned int cnt[HCHUNK / 2];
    int b = blockIdx.x;
    int npass = (n + HCHUNK - 1) / HCHUNK;
    int per = (ne + HBLOCKS - 1) / HBLOCKS;
    int e0 = b * per, e1 = min(e0 + per, ne);
    for (int p = 0; p < npass; p++) {
        int base = p * HCHUNK;
        for (int i = threadIdx.x; i < HCHUNK / 2; i += 256) cnt[i] = 0;
        __syncthreads();
        const unsigned int* pf = prefix + ((size_t)p * HBLOCKS + b) * (HCHUNK / 2);
        for (int e = e0 + threadIdx.x; e < e1; e += 256) {
            int d = dst[e] - base;
            if ((unsigned)d < (unsigned)HCHUNK) {
                int sh = (d & 1) * 16;
                unsigned old = atomicAdd(&cnt[d >> 1], 1u << sh);  // LDS atomic only
                int rank = (int)((old >> sh) & 0xffffu);
                int pos = rp[base + d] + (int)((pf[d >> 1] >> sh) & 0xffffu) + rank;
                esrc[pos] = src[e];
            }
        }
        __syncthreads();
    }
}

// ---------------- GEMM: H[m][c] = sum_k (X[m][k]*rs[m]) * W[k][c]  (+ rs[m]*v[c]) ----
template <int NCOL, bool HAS_V>
__global__ __launch_bounds__(256) void gemm_k(
    const float* __restrict__ X, const float* __restrict__ W,
    const float* __restrict__ rs, const float* __restrict__ vvec,
    float* __restrict__ H, int n) {
    constexpr int BK = 32;
    constexpr int CG = NCOL / 4;
    constexpr int RG = 256 / CG;
    constexpr int BM = RG * 4;
    __shared__ float Xs[BK][BM + 4];
    __shared__ float Ws[BK][NCOL];
    int tid = threadIdx.x;
    int tx = tid % CG;
    int ty = tid / CG;
    int row0 = blockIdx.x * BM;
    float acc[4][4] = {};
    for (int k0 = 0; k0 < NFEAT; k0 += BK) {
        for (int idx = tid; idx < BK * NCOL; idx += 256) {
            int k = idx / NCOL, c = idx % NCOL;
            Ws[k][c] = W[(k0 + k) * NCOL + c];
        }
        for (int idx = tid; idx < BM * BK; idx += 256) {
            int m = idx / BK, k = idx % BK;
            int gm = row0 + m;
            Xs[k][m] = (gm < n) ? X[(size_t)gm * NFEAT + k0 + k] * rs[gm] : 0.f;
        }
        __syncthreads();
#pragma unroll
        for (int k = 0; k < BK; k++) {
            float4 a = *(const float4*)&Xs[k][ty * 4];
            float4 b = *(const float4*)&Ws[k][tx * 4];
            float av[4] = {a.x, a.y, a.z, a.w};
            float bv[4] = {b.x, b.y, b.z, b.w};
#pragma unroll
            for (int i = 0; i < 4; i++)
#pragma unroll
                for (int j = 0; j < 4; j++) acc[i][j] += av[i] * bv[j];
        }
        __syncthreads();
    }
#pragma unroll
    for (int i = 0; i < 4; i++) {
        int gm = row0 + ty * 4 + i;
        if (gm < n) {
            float4 o;
            o.x = acc[i][0]; o.y = acc[i][1]; o.z = acc[i][2]; o.w = acc[i][3];
            if (HAS_V) {
                float sc = rs[gm];
                o.x += sc * vvec[tx * 4 + 0];
                o.y += sc * vvec[tx * 4 + 1];
                o.z += sc * vvec[tx * 4 + 2];
                o.w += sc * vvec[tx * 4 + 3];
            }
            *(float4*)&H[(size_t)gm * NCOL + tx * 4] = o;
        }
    }
}

// ---------------- CSR aggregation ----------------
template <int F, bool RELU>
__global__ void agg_k(const float* __restrict__ H, const int* __restrict__ rp,
                      const int* __restrict__ esrc, const float* __restrict__ nd,
                      const float* __restrict__ bias, float* __restrict__ out) {
    int node = blockIdx.x;
    int c = threadIdx.x;
    int e0 = rp[node], e1 = rp[node + 1];
    float acc = 0.f;
    int e = e0;
    for (; e + 4 <= e1; e += 4) {
        int s0 = esrc[e], s1 = esrc[e + 1], s2 = esrc[e + 2], s3 = esrc[e + 3];
        float v0 = H[(size_t)s0 * F + c];
        float v1 = H[(size_t)s1 * F + c];
        float v2 = H[(size_t)s2 * F + c];
        float v3 = H[(size_t)s3 * F + c];
        acc += (v0 + v1) + (v2 + v3);
    }
    for (; e < e1; e++) acc += H[(size_t)esrc[e] * F + c];
    float val = acc * nd[node] + bias[c];
    if (RELU) val = fmaxf(val, 0.f);
    out[(size_t)node * F + c] = val;
}

// ---------------- BN stats (two-stage, atomic-free, high-parallelism) ----------------
constexpr int CSB = 1024;  // stage-1 blocks

__global__ __launch_bounds__(256) void colstats1_k(const float* __restrict__ X,
                                                   float* __restrict__ psum,
                                                   float* __restrict__ psq, int n) {
    __shared__ float sh[256];
    int t = threadIdx.x;
    int c = t & 127;
    int half = t >> 7;             // 0 or 1
    int rows_per = (n + CSB - 1) / CSB;
    int r0 = blockIdx.x * rows_per;
    int r1 = min(r0 + rows_per, n);
    float s = 0.f, sq = 0.f;
    for (int r = r0 + half; r < r1; r += 2) {
        float v = X[(size_t)r * 128 + c];
        s += v;
        sq += v * v;
    }
    sh[t] = s;
    __syncthreads();
    if (half == 0) psum[(size_t)c * CSB + blockIdx.x] = s + sh[t + 128];
    __syncthreads();
    sh[t] = sq;
    __syncthreads();
    if (half == 0) psq[(size_t)c * CSB + blockIdx.x] = sq + sh[t + 128];
}

__global__ __launch_bounds__(256) void colstats2_k(const float* __restrict__ psum,
                                                   const float* __restrict__ psq,
                                                   float* __restrict__ colsum,
                                                   float* __restrict__ colsq) {
    __shared__ float sh[256];
    int c = blockIdx.x;
    int t = threadIdx.x;
    float s = 0.f, sq = 0.f;
#pragma unroll
    for (int i = 0; i < CSB / 256; i++) {
        s += psum[(size_t)c * CSB + i * 256 + t];
        sq += psq[(size_t)c * CSB + i * 256 + t];
    }
    sh[t] = s;
    __syncthreads();
    for (int off = 128; off > 0; off >>= 1) {
        if (t < off) sh[t] += sh[t + off];
        __syncthreads();
    }
    if (t == 0) colsum[c] = sh[0];
    __syncthreads();
    sh[t] = sq;
    __syncthreads();
    for (int off = 128; off > 0; off >>= 1) {
        if (t < off) sh[t] += sh[t + off];
        __syncthreads();
    }
    if (t == 0) colsq[c] = sh[0];
}

__global__ void bn_prep_k(const float* __restrict__ colsum, const float* __restrict__ colsq,
                          const float* __restrict__ gamma, const float* __restrict__ beta,
                          const float* __restrict__ W2, float* __restrict__ W2p,
                          float* __restrict__ v2, float n) {
    __shared__ float s_s[128], s_t[128];
    int c = threadIdx.x;
    float mu = colsum[c] / n;
    float var = colsq[c] / n - mu * mu;
    float s = gamma[c] * rsqrtf(var + 1e-5f);
    float t = beta[c] - mu * s;
    s_s[c] = s;
    s_t[c] = t;
    __syncthreads();
    float acc = 0.f;
    for (int k = 0; k < 128; k++) {
        float w = W2[k * 128 + c];
        W2p[k * 128 + c] = s_s[k] * w;
        acc += s_t[k] * w;
    }
    v2[c] = acc;
}

extern "C" void kernel_launch(void* const* d_in, const int* in_sizes, int n_in,
                              void* d_out, int out_size, void* d_ws, size_t ws_size,
                              hipStream_t stream) {
    const float* feat = (const float*)d_in[0];
    const int* src = (const int*)d_in[1];
    const int* dst = (const int*)d_in[2];
    const float* W1 = (const float*)d_in[3];
    const float* b1 = (const float*)d_in[4];
    const float* gamma1 = (const float*)d_in[5];
    const float* beta1 = (const float*)d_in[6];
    const float* W2 = (const float*)d_in[7];
    const float* b2 = (const float*)d_in[8];
    const float* W3 = (const float*)d_in[9];
    const float* b3 = (const float*)d_in[10];
    float* out = (float*)d_out;

    int n = in_sizes[0] / NFEAT;
    int ne = in_sizes[1];
    int npass = (n + HCHUNK - 1) / HCHUNK;

    char* ws = (char*)d_ws;
    size_t off = 0;
    auto carve = [&](size_t bytes) -> void* {
        void* p = ws + off;
        off += (bytes + 255) & ~(size_t)255;
        return p;
    };
    float* h    = (float*)carve((size_t)n * NFEAT * 4);
    float* x    = (float*)carve((size_t)n * NFEAT * 4);
    int* esrc   = (int*)carve((size_t)ne * 4);
    int* dout_  = (int*)carve((size_t)n * 4);
    int* din_   = (int*)carve((size_t)n * 4);
    float* ns   = (float*)carve((size_t)n * 4);
    float* ndv  = (float*)carve((size_t)n * 4);
    int* rp     = (int*)carve((size_t)(n + 1) * 4);
    int* parts  = (int*)carve(512 * 4);
    float* psum = (float*)carve((size_t)128 * CSB * 4);
    float* psq  = (float*)carve((size_t)128 * CSB * 4);
    float* colsum = (float*)carve(128 * 4);
    float* colsq  = (float*)carve(128 * 4);
    float* W2p  = (float*)carve(128 * 128 * 4);
    float* v2   = (float*)carve(128 * 4);

    // histogram partials alias h (h first written by gemm1, after CSR build)
    unsigned int* hpart = (unsigned int*)h;

    int nbl = (n + 255) / 256;
    int sbl = (npass * (HCHUNK / 2) + 255) / 256;

    hist_k<<<HBLOCKS, 256, 0, stream>>>(src, ne, n, hpart);
    sum_prefix_k<false><<<sbl, 256, 0, stream>>>(hpart, dout_, n, npass);
    hist_k<<<HBLOCKS, 256, 0, stream>>>(dst, ne, n, hpart);
    sum_prefix_k<true><<<sbl, 256, 0, stream>>>(hpart, din_, n, npass);

    norms_k<<<nbl, 256, 0, stream>>>(dout_, din_, ns, ndv, n);
    scan1_k<<<nbl, 256, 0, stream>>>(din_, rp, parts, n);
    scan2_k<<<1, 512, 0, stream>>>(parts, nbl);
    scan3_k<<<nbl, 256, 0, stream>>>(rp, parts, din_, n);
    fill2_k<<<HBLOCKS, 256, 0, stream>>>(src, dst, rp, hpart, esrc, ne, n);

    // layer 1: relu(conv(features, W1, b1))
    gemm_k<128, false><<<(n + 31) / 32, 256, 0, stream>>>(feat, W1, ns, nullptr, h, n);
    agg_k<128, true><<<n, 128, 0, stream>>>(h, rp, esrc, ndv, b1, x);

    // batchnorm folded into W2 (two-stage atomic-free stats)
    colstats1_k<<<CSB, 256, 0, stream>>>(x, psum, psq, n);
    colstats2_k<<<128, 256, 0, stream>>>(psum, psq, colsum, colsq);
    bn_prep_k<<<1, 128, 0, stream>>>(colsum, colsq, gamma1, beta1, W2, W2p, v2, (float)n);

    // layer 2: relu(conv(BN(x), W2, b2))
    gemm_k<128, true><<<(n + 31) / 32, 256, 0, stream>>>(x, W2p, ns, v2, h, n);
    agg_k<128, true><<<n, 128, 0, stream>>>(h, rp, esrc, ndv, b2, x);

    // layer 3: conv(x, W3, b3) -> out
    gemm_k<64, false><<<(n + 63) / 64, 256, 0, stream>>>(x, W3, ns, nullptr, h, n);
    agg_k<64, false><<<n, 64, 0, stream>>>(h, rp, esrc, ndv, b3, out);
}

// Round 5
// 598.347 us; speedup vs baseline: 1.4917x; 1.2192x over previous
//
#include <hip/hip_runtime.h>

#define NFEAT 128

// ---------------- LDS-privatized degree histogram (no global atomics) ----------------
// Grid = (HBLOCKS edge-slices, npass node-chunks): each block reads its slice once,
// filters for its chunk. 64 KB LDS/block -> 2 blocks/CU.
constexpr int HCHUNK = 32768;
constexpr int HBLOCKS = 128;

__global__ __launch_bounds__(256) void hist_k(const int* __restrict__ idx, int ne, int n,
                                              unsigned int* __restrict__ partials) {
    __shared__ unsigned int cnt[HCHUNK / 2];
    int b = blockIdx.x;
    int p = blockIdx.y;
    int per = (ne + HBLOCKS - 1) / HBLOCKS;
    int e0 = b * per, e1 = min(e0 + per, ne);
    int base = p * HCHUNK;
    for (int i = threadIdx.x; i < HCHUNK / 2; i += 256) cnt[i] = 0;
    __syncthreads();
    for (int e = e0 + threadIdx.x; e < e1; e += 256) {
        int d = idx[e] - base;
        if ((unsigned)d < (unsigned)HCHUNK) {
            atomicAdd(&cnt[d >> 1], 1u << ((d & 1) * 16));
        }
    }
    __syncthreads();
    unsigned int* dstp = partials + ((size_t)p * HBLOCKS + b) * (HCHUNK / 2);
    for (int i = threadIdx.x; i < HCHUNK / 2; i += 256) dstp[i] = cnt[i];
}

template <bool PFX>
__global__ void sum_prefix_k(unsigned int* __restrict__ partials, int* __restrict__ deg,
                             int n, int npass) {
    int slot = blockIdx.x * 256 + threadIdx.x;
    int total = npass * (HCHUNK / 2);
    if (slot >= total) return;
    int p = slot / (HCHUNK / 2);
    int j2 = slot - p * (HCHUNK / 2);
    unsigned int* base = partials + (size_t)p * HBLOCKS * (HCHUNK / 2) + j2;
    unsigned lo = 0, hi = 0;
    for (int b = 0; b < HBLOCKS; b++) {
        unsigned v = base[(size_t)b * (HCHUNK / 2)];
        if (PFX) base[(size_t)b * (HCHUNK / 2)] = lo | (hi << 16);
        lo += v & 0xffffu;
        hi += v >> 16;
    }
    int node = p * HCHUNK + 2 * j2;
    if (node < n) deg[node] = (int)lo;
    if (node + 1 < n) deg[node + 1] = (int)hi;
}

__global__ void norms_k(const int* __restrict__ dout, const int* __restrict__ din,
                        float* __restrict__ ns, float* __restrict__ nd, int n) {
    int i = blockIdx.x * 256 + threadIdx.x;
    if (i < n) {
        ns[i] = rsqrtf(fmaxf((float)dout[i], 1.f));
        nd[i] = rsqrtf(fmaxf((float)din[i], 1.f));
    }
}

// ---------------- exclusive scan of deg_in -> row_ptr ----------------
__global__ void scan1_k(const int* __restrict__ deg, int* __restrict__ rp,
                        int* __restrict__ partials, int n) {
    __shared__ int tmp[256];
    int t = threadIdx.x;
    int i = blockIdx.x * 256 + t;
    int v = (i < n) ? deg[i] : 0;
    tmp[t] = v;
    __syncthreads();
    int val = v;
    for (int off = 1; off < 256; off <<= 1) {
        int add = (t >= off) ? tmp[t - off] : 0;
        __syncthreads();
        val += add;
        tmp[t] = val;
        __syncthreads();
    }
    if (i < n) rp[i] = val - v;
    if (t == 255) partials[blockIdx.x] = val;
}

__global__ void scan2_k(int* __restrict__ partials, int nb) {
    __shared__ int tmp[512];
    int t = threadIdx.x;
    int v = (t < nb) ? partials[t] : 0;
    tmp[t] = v;
    __syncthreads();
    int val = v;
    for (int off = 1; off < 512; off <<= 1) {
        int add = (t >= off) ? tmp[t - off] : 0;
        __syncthreads();
        val += add;
        tmp[t] = val;
        __syncthreads();
    }
    if (t < nb) partials[t] = val - v;
}

__global__ void scan3_k(int* __restrict__ rp, const int* __restrict__ partials,
                        const int* __restrict__ deg, int n) {
    int i = blockIdx.x * 256 + threadIdx.x;
    if (i < n) {
        int r = rp[i] + partials[blockIdx.x];
        rp[i] = r;
        if (i == n - 1) rp[n] = r + deg[i];
    }
}

// ---------------- atomic-free CSR fill (counting-sort scatter, pass-parallel) -------
__global__ __launch_bounds__(256) void fill2_k(const int* __restrict__ src,
                                               const int* __restrict__ dst,
                                               const int* __restrict__ rp,
                                               const unsigned int* __restrict__ prefix,
                                               int* __restrict__ esrc, int ne, int n) {
    __shared__ unsigned int cnt[HCHUNK / 2];
    int b = blockIdx.x;
    int p = blockIdx.y;
    int per = (ne + HBLOCKS - 1) / HBLOCKS;
    int e0 = b * per, e1 = min(e0 + per, ne);
    int base = p * HCHUNK;
    for (int i = threadIdx.x; i < HCHUNK / 2; i += 256) cnt[i] = 0;
    __syncthreads();
    const unsigned int* pf = prefix + ((size_t)p * HBLOCKS + b) * (HCHUNK / 2);
    for (int e = e0 + threadIdx.x; e < e1; e += 256) {
        int d = dst[e] - base;
        if ((unsigned)d < (unsigned)HCHUNK) {
            int sh = (d & 1) * 16;
            unsigned old = atomicAdd(&cnt[d >> 1], 1u << sh);  // LDS atomic only
            int rank = (int)((old >> sh) & 0xffffu);
            int pos = rp[base + d] + (int)((pf[d >> 1] >> sh) & 0xffffu) + rank;
            esrc[pos] = src[e];
        }
    }
}

// ---------------- GEMM: H[m][c] = sum_k (X[m][k]*rs[m]) * W[k][c]  (+ rs[m]*v[c]) ----
template <int NCOL, bool HAS_V>
__global__ __launch_bounds__(256) void gemm_k(
    const float* __restrict__ X, const float* __restrict__ W,
    const float* __restrict__ rs, const float* __restrict__ vvec,
    float* __restrict__ H, int n) {
    constexpr int BK = 32;
    constexpr int CG = NCOL / 4;
    constexpr int RG = 256 / CG;
    constexpr int BM = RG * 4;
    __shared__ float Xs[BK][BM + 4];
    __shared__ float Ws[BK][NCOL];
    int tid = threadIdx.x;
    int tx = tid % CG;
    int ty = tid / CG;
    int row0 = blockIdx.x * BM;
    float acc[4][4] = {};
    for (int k0 = 0; k0 < NFEAT; k0 += BK) {
        for (int idx = tid; idx < BK * NCOL; idx += 256) {
            int k = idx / NCOL, c = idx % NCOL;
            Ws[k][c] = W[(k0 + k) * NCOL + c];
        }
        for (int idx = tid; idx < BM * BK; idx += 256) {
            int m = idx / BK, k = idx % BK;
            int gm = row0 + m;
            Xs[k][m] = (gm < n) ? X[(size_t)gm * NFEAT + k0 + k] * rs[gm] : 0.f;
        }
        __syncthreads();
#pragma unroll
        for (int k = 0; k < BK; k++) {
            float4 a = *(const float4*)&Xs[k][ty * 4];
            float4 b = *(const float4*)&Ws[k][tx * 4];
            float av[4] = {a.x, a.y, a.z, a.w};
            float bv[4] = {b.x, b.y, b.z, b.w};
#pragma unroll
            for (int i = 0; i < 4; i++)
#pragma unroll
                for (int j = 0; j < 4; j++) acc[i][j] += av[i] * bv[j];
        }
        __syncthreads();
    }
#pragma unroll
    for (int i = 0; i < 4; i++) {
        int gm = row0 + ty * 4 + i;
        if (gm < n) {
            float4 o;
            o.x = acc[i][0]; o.y = acc[i][1]; o.z = acc[i][2]; o.w = acc[i][3];
            if (HAS_V) {
                float sc = rs[gm];
                o.x += sc * vvec[tx * 4 + 0];
                o.y += sc * vvec[tx * 4 + 1];
                o.z += sc * vvec[tx * 4 + 2];
                o.w += sc * vvec[tx * 4 + 3];
            }
            *(float4*)&H[(size_t)gm * NCOL + tx * 4] = o;
        }
    }
}

// ---------------- CSR aggregation ----------------
template <int F, bool RELU>
__global__ void agg_k(const float* __restrict__ H, const int* __restrict__ rp,
                      const int* __restrict__ esrc, const float* __restrict__ nd,
                      const float* __restrict__ bias, float* __restrict__ out) {
    int node = blockIdx.x;
    int c = threadIdx.x;
    int e0 = rp[node], e1 = rp[node + 1];
    float acc = 0.f;
    int e = e0;
    for (; e + 4 <= e1; e += 4) {
        int s0 = esrc[e], s1 = esrc[e + 1], s2 = esrc[e + 2], s3 = esrc[e + 3];
        float v0 = H[(size_t)s0 * F + c];
        float v1 = H[(size_t)s1 * F + c];
        float v2 = H[(size_t)s2 * F + c];
        float v3 = H[(size_t)s3 * F + c];
        acc += (v0 + v1) + (v2 + v3);
    }
    for (; e < e1; e++) acc += H[(size_t)esrc[e] * F + c];
    float val = acc * nd[node] + bias[c];
    if (RELU) val = fmaxf(val, 0.f);
    out[(size_t)node * F + c] = val;
}

// ---------------- BN stats (two-stage, atomic-free) ----------------
constexpr int CSB = 1024;

__global__ __launch_bounds__(256) void colstats1_k(const float* __restrict__ X,
                                                   float* __restrict__ psum,
                                                   float* __restrict__ psq, int n) {
    __shared__ float sh[256];
    int t = threadIdx.x;
    int c = t & 127;
    int half = t >> 7;
    int rows_per = (n + CSB - 1) / CSB;
    int r0 = blockIdx.x * rows_per;
    int r1 = min(r0 + rows_per, n);
    float s = 0.f, sq = 0.f;
    for (int r = r0 + half; r < r1; r += 2) {
        float v = X[(size_t)r * 128 + c];
        s += v;
        sq += v * v;
    }
    sh[t] = s;
    __syncthreads();
    if (half == 0) psum[(size_t)c * CSB + blockIdx.x] = s + sh[t + 128];
    __syncthreads();
    sh[t] = sq;
    __syncthreads();
    if (half == 0) psq[(size_t)c * CSB + blockIdx.x] = sq + sh[t + 128];
}

__global__ __launch_bounds__(256) void colstats2_k(const float* __restrict__ psum,
                                                   const float* __restrict__ psq,
                                                   float* __restrict__ colsum,
                                                   float* __restrict__ colsq) {
    __shared__ float sh[256];
    int c = blockIdx.x;
    int t = threadIdx.x;
    float s = 0.f, sq = 0.f;
#pragma unroll
    for (int i = 0; i < CSB / 256; i++) {
        s += psum[(size_t)c * CSB + i * 256 + t];
        sq += psq[(size_t)c * CSB + i * 256 + t];
    }
    sh[t] = s;
    __syncthreads();
    for (int off = 128; off > 0; off >>= 1) {
        if (t < off) sh[t] += sh[t + off];
        __syncthreads();
    }
    if (t == 0) colsum[c] = sh[0];
    __syncthreads();
    sh[t] = sq;
    __syncthreads();
    for (int off = 128; off > 0; off >>= 1) {
        if (t < off) sh[t] += sh[t + off];
        __syncthreads();
    }
    if (t == 0) colsq[c] = sh[0];
}

__global__ void bn_prep_k(const float* __restrict__ colsum, const float* __restrict__ colsq,
                          const float* __restrict__ gamma, const float* __restrict__ beta,
                          const float* __restrict__ W2, float* __restrict__ W2p,
                          float* __restrict__ v2, float n) {
    __shared__ float s_s[128], s_t[128];
    int c = threadIdx.x;
    float mu = colsum[c] / n;
    float var = colsq[c] / n - mu * mu;
    float s = gamma[c] * rsqrtf(var + 1e-5f);
    float t = beta[c] - mu * s;
    s_s[c] = s;
    s_t[c] = t;
    __syncthreads();
    float acc = 0.f;
    for (int k = 0; k < 128; k++) {
        float w = W2[k * 128 + c];
        W2p[k * 128 + c] = s_s[k] * w;
        acc += s_t[k] * w;
    }
    v2[c] = acc;
}

extern "C" void kernel_launch(void* const* d_in, const int* in_sizes, int n_in,
                              void* d_out, int out_size, void* d_ws, size_t ws_size,
                              hipStream_t stream) {
    const float* feat = (const float*)d_in[0];
    const int* src = (const int*)d_in[1];
    const int* dst = (const int*)d_in[2];
    const float* W1 = (const float*)d_in[3];
    const float* b1 = (const float*)d_in[4];
    const float* gamma1 = (const float*)d_in[5];
    const float* beta1 = (const float*)d_in[6];
    const float* W2 = (const float*)d_in[7];
    const float* b2 = (const float*)d_in[8];
    const float* W3 = (const float*)d_in[9];
    const float* b3 = (const float*)d_in[10];
    float* out = (float*)d_out;

    int n = in_sizes[0] / NFEAT;
    int ne = in_sizes[1];
    int npass = (n + HCHUNK - 1) / HCHUNK;

    char* ws = (char*)d_ws;
    size_t off = 0;
    auto carve = [&](size_t bytes) -> void* {
        void* p = ws + off;
        off += (bytes + 255) & ~(size_t)255;
        return p;
    };
    float* h    = (float*)carve((size_t)n * NFEAT * 4);
    float* x    = (float*)carve((size_t)n * NFEAT * 4);
    int* esrc   = (int*)carve((size_t)ne * 4);
    int* dout_  = (int*)carve((size_t)n * 4);
    int* din_   = (int*)carve((size_t)n * 4);
    float* ns   = (float*)carve((size_t)n * 4);
    float* ndv  = (float*)carve((size_t)n * 4);
    int* rp     = (int*)carve((size_t)(n + 1) * 4);
    int* parts  = (int*)carve(512 * 4);
    float* psum = (float*)carve((size_t)128 * CSB * 4);
    float* psq  = (float*)carve((size_t)128 * CSB * 4);
    float* colsum = (float*)carve(128 * 4);
    float* colsq  = (float*)carve(128 * 4);
    float* W2p  = (float*)carve(128 * 128 * 4);
    float* v2   = (float*)carve(128 * 4);

    // histogram partials alias h (h first written by gemm1, after CSR build)
    unsigned int* hpart = (unsigned int*)h;

    int nbl = (n + 255) / 256;
    int sbl = (npass * (HCHUNK / 2) + 255) / 256;
    dim3 hgrid(HBLOCKS, npass);

    hist_k<<<hgrid, 256, 0, stream>>>(src, ne, n, hpart);
    sum_prefix_k<false><<<sbl, 256, 0, stream>>>(hpart, dout_, n, npass);
    hist_k<<<hgrid, 256, 0, stream>>>(dst, ne, n, hpart);
    sum_prefix_k<true><<<sbl, 256, 0, stream>>>(hpart, din_, n, npass);

    norms_k<<<nbl, 256, 0, stream>>>(dout_, din_, ns, ndv, n);
    scan1_k<<<nbl, 256, 0, stream>>>(din_, rp, parts, n);
    scan2_k<<<1, 512, 0, stream>>>(parts, nbl);
    scan3_k<<<nbl, 256, 0, stream>>>(rp, parts, din_, n);
    fill2_k<<<hgrid, 256, 0, stream>>>(src, dst, rp, hpart, esrc, ne, n);

    // layer 1: relu(conv(features, W1, b1))
    gemm_k<128, false><<<(n + 31) / 32, 256, 0, stream>>>(feat, W1, ns, nullptr, h, n);
    agg_k<128, true><<<n, 128, 0, stream>>>(h, rp, esrc, ndv, b1, x);

    // batchnorm folded into W2
    colstats1_k<<<CSB, 256, 0, stream>>>(x, psum, psq, n);
    colstats2_k<<<128, 256, 0, stream>>>(psum, psq, colsum, colsq);
    bn_prep_k<<<1, 128, 0, stream>>>(colsum, colsq, gamma1, beta1, W2, W2p, v2, (float)n);

    // layer 2: relu(conv(BN(x), W2, b2))
    gemm_k<128, true><<<(n + 31) / 32, 256, 0, stream>>>(x, W2p, ns, v2, h, n);
    agg_k<128, true><<<n, 128, 0, stream>>>(h, rp, esrc, ndv, b2, x);

    // layer 3: conv(x, W3, b3) -> out
    gemm_k<64, false><<<(n + 63) / 64, 256, 0, stream>>>(x, W3, ns, nullptr, h, n);
    agg_k<64, false><<<n, 64, 0, stream>>>(h, rp, esrc, ndv, b3, out);
}